// Round 8
// baseline (1080.090 us; speedup 1.0000x reference)
//
#include <hip/hip_runtime.h>

#define WN 32          // WIDTH
#define HID 8          // WIDTH/4
#define DEPTH 4
#define GPB 16         // node-groups per block (16 threads x 2 channels each)
#define NBIN 1024      // degree bins for node ordering

typedef float fvec4 __attribute__((ext_vector_type(4)));

__global__ void zero_kernel(int* __restrict__ cnt, int* __restrict__ cursor,
                            int* __restrict__ bins, int* __restrict__ bin_cursor, int n) {
    int i = blockIdx.x * blockDim.x + threadIdx.x;
    if (i < n) { cnt[i] = 0; cursor[i] = 0; }
    if (i < NBIN) { bins[i] = 0; bin_cursor[i] = 0; }
}

__global__ void count_kernel(const int* __restrict__ eidx, int* __restrict__ cnt, int e_cnt) {
    int e = blockIdx.x * blockDim.x + threadIdx.x;
    if (e >= e_cnt) return;
    atomicAdd(&cnt[eidx[e_cnt + e]], 1);
}

// Single-block exclusive scan over cnt -> row_ptr[n+1]; also inv = 1/max(cnt,1)
// and degree histogram (clamped to NBIN-1) for the node ordering.
__global__ void scan_kernel(const int* __restrict__ cnt, int* __restrict__ row_ptr,
                            float* __restrict__ inv, int* __restrict__ bins, int n) {
    __shared__ int s_wave[16];
    int t = threadIdx.x;
    int lane = t & 63;
    int wv = t >> 6;                 // 16 waves of 64
    int offset = 0;
    for (int base = 0; base < n; base += 1024) {
        int i = base + t;
        int v = (i < n) ? cnt[i] : 0;
        int x = v;
#pragma unroll
        for (int d = 1; d < 64; d <<= 1) {
            int y = __shfl_up(x, d, 64);
            if (lane >= d) x += y;
        }
        if (lane == 63) s_wave[wv] = x;
        __syncthreads();
        if (wv == 0 && lane < 16) {
            int y = s_wave[lane];
#pragma unroll
            for (int d = 1; d < 16; d <<= 1) {
                int z = __shfl_up(y, d, 64);
                if (lane >= d) y += z;
            }
            s_wave[lane] = y;        // inclusive over wave sums
        }
        __syncthreads();
        int waveoff = (wv > 0) ? s_wave[wv - 1] : 0;
        int total = s_wave[15];
        int incl = x + waveoff + offset;
        if (i < n) {
            row_ptr[i + 1] = incl;
            inv[i] = 1.0f / (float)(v > 1 ? v : 1);
            int d = v < (NBIN - 1) ? v : (NBIN - 1);
            atomicAdd(&bins[d], 1);
        }
        offset += total;
        __syncthreads();
    }
    if (t == 0) row_ptr[0] = 0;
}

// Single-block exclusive scan of the 1024 degree bins.
__global__ void bin_scan_kernel(const int* __restrict__ bins, int* __restrict__ bin_base) {
    __shared__ int s_wave[16];
    int t = threadIdx.x;
    int lane = t & 63;
    int wv = t >> 6;
    int v = bins[t];
    int x = v;
#pragma unroll
    for (int d = 1; d < 64; d <<= 1) {
        int y = __shfl_up(x, d, 64);
        if (lane >= d) x += y;
    }
    if (lane == 63) s_wave[wv] = x;
    __syncthreads();
    if (wv == 0 && lane < 16) {
        int y = s_wave[lane];
#pragma unroll
        for (int d = 1; d < 16; d <<= 1) {
            int z = __shfl_up(y, d, 64);
            if (lane >= d) y += z;
        }
        s_wave[lane] = y;
    }
    __syncthreads();
    int waveoff = (wv > 0) ? s_wave[wv - 1] : 0;
    bin_base[t] = x + waveoff - v;   // exclusive
}

// Scatter node ids into degree-sorted order[] (counting sort by degree).
__global__ void order_kernel(const int* __restrict__ cnt, const int* __restrict__ bin_base,
                             int* __restrict__ bin_cursor, int* __restrict__ order, int n) {
    int i = blockIdx.x * blockDim.x + threadIdx.x;
    if (i >= n) return;
    int v = cnt[i];
    int d = v < (NBIN - 1) ? v : (NBIN - 1);
    int pos = bin_base[d] + atomicAdd(&bin_cursor[d], 1);
    order[pos] = i;
}

// Permute edges into dst-CSR order as ONE packed 16B record per edge:
// rec[pos] = {src_bits, ea0, ea1, ea2} -> single dirty 64B line per edge.
__global__ void scatter_kernel(const int* __restrict__ eidx, const float* __restrict__ ea,
                               const int* __restrict__ row_ptr, int* __restrict__ cursor,
                               fvec4* __restrict__ rec, int e_cnt) {
    int e = blockIdx.x * blockDim.x + threadIdx.x;
    if (e >= e_cnt) return;
    int src = eidx[e];
    int dst = eidx[e_cnt + e];
    int pos = row_ptr[dst] + atomicAdd(&cursor[dst], 1);
    fvec4 r;
    r.x = __int_as_float(src);
    r.y = ea[3 * e];
    r.z = ea[3 * e + 1];
    r.w = ea[3 * e + 2];
    rec[pos] = r;
}

__global__ void h0_kernel(const float* __restrict__ x, const float* __restrict__ fc1_w,
                          const float* __restrict__ fc1_b, float* __restrict__ h, int n) {
    __shared__ float s_w[WN * 3];
    __shared__ float s_b[WN];
    int t = threadIdx.x;
    if (t < WN * 3) s_w[t] = fc1_w[t];
    if (t < WN) s_b[t] = fc1_b[t];
    __syncthreads();
    int i = blockIdx.x * blockDim.x + t;
    if (i >= n) return;
    float x0 = x[3 * i], x1 = x[3 * i + 1], x2 = x[3 * i + 2];
#pragma unroll
    for (int j = 0; j < WN; j++) {
        h[(size_t)i * WN + j] = s_b[j] + s_w[j * 3] * x0 + s_w[j * 3 + 1] * x1 + s_w[j * 3 + 2] * x2;
    }
}

// Cooperative gather, 2-channel register blocking, degree-sorted node order.
// 16 node-groups x 16 threads; thread owns channels (2tc, 2tc+1). Blocks get
// degree-adjacent nodes -> nchunk is tight, masked waste ~0. s_root dropped
// (root is 4KB, L1-resident) -> 23KB LDS -> 6 blocks/CU.
__global__ void gather2_kernel(const int* __restrict__ row_ptr, const fvec4* __restrict__ rec,
                               const int* __restrict__ order,
                               const float* __restrict__ h_in, float* __restrict__ h_out,
                               const float* __restrict__ inv,
                               const float* __restrict__ kw1, const float* __restrict__ kb1,
                               const float* __restrict__ kw2, const float* __restrict__ kb2,
                               const float* __restrict__ root, const float* __restrict__ cbias,
                               int n) {
    __shared__ float s_h[GPB * 34];          // group stride 34
    __shared__ int   s_src[GPB][33];
    __shared__ fvec4 s_hid_u[GPB][33];
    __shared__ fvec4 s_hid_v[GPB][33];
    __shared__ int   s_maxdeg;

    int t = threadIdx.x;
    if (t == 0) s_maxdeg = 0;

    int grp = t >> 4;          // 0..15
    int tc  = t & 15;          // 0..15, channels 2tc, 2tc+1
    int idx = blockIdx.x * GPB + grp;
    bool valid = idx < n;
    int node = valid ? order[idx] : 0;

    // per-thread weight columns for 2 output channels (16 floats, coalesced)
    const fvec4* kwp = (const fvec4*)(kw2 + tc * 16);
    fvec4 wa0 = kwp[0], wa1 = kwp[1];        // channel 2tc
    fvec4 wb0 = kwp[2], wb1 = kwp[3];        // channel 2tc+1
    float2 b2 = *(const float2*)(kb2 + 2 * tc);
    float2 cb = *(const float2*)(cbias + 2 * tc);

    int e0 = 0, e1 = 0;
    float2 hself = {0.0f, 0.0f};
    if (valid) {
        e0 = row_ptr[node];
        e1 = row_ptr[node + 1];
        hself = *(const float2*)(h_in + (size_t)node * WN + 2 * tc);
    }
    *(float2*)&s_h[grp * 34 + 2 * tc] = hself;
    int deg = e1 - e0;
    __syncthreads();                         // s_maxdeg init + s_h visible
    if (valid && tc == 0 && deg > 0) atomicMax(&s_maxdeg, deg);
    __syncthreads();
    int nchunk = (s_maxdeg + 31) >> 5;       // block-uniform; tight (degree-sorted)

    float acc0 = 0.0f, acc1 = 0.0f;
    for (int cs = 0; cs < nchunk; cs++) {
        int ebase = e0 + (cs << 5);
#pragma unroll
        for (int s = 0; s < 2; s++) {
            int li = tc + (s << 4);
            int e = ebase + li;
            if (e < e1) {
                fvec4 r = rec[e];
                s_src[grp][li] = __float_as_int(r.x);
                float hv[HID];
#pragma unroll
                for (int j = 0; j < HID; j++) {
                    float u = kb1[j] + kw1[3 * j] * r.y + kw1[3 * j + 1] * r.z + kw1[3 * j + 2] * r.w;
                    hv[j] = u > 0.0f ? u : 0.0f;
                }
                fvec4 lo, hi;
                lo.x = hv[0]; lo.y = hv[1]; lo.z = hv[2]; lo.w = hv[3];
                hi.x = hv[4]; hi.y = hv[5]; hi.z = hv[6]; hi.w = hv[7];
                s_hid_u[grp][li] = lo;
                s_hid_v[grp][li] = hi;
            }
        }
        __syncthreads();
        int rem = e1 - ebase;
        int cnt = rem < 32 ? rem : 32;       // <=0 for finished/invalid groups
#pragma unroll 4
        for (int i = 0; i < cnt; i++) {
            int src = s_src[grp][i];
            fvec4 u = s_hid_u[grp][i];
            fvec4 v = s_hid_v[grp][i];
            float w0 = b2.x + wa0.x * u.x + wa0.y * u.y + wa0.z * u.z + wa0.w * u.w
                            + wa1.x * v.x + wa1.y * v.y + wa1.z * v.z + wa1.w * v.w;
            float w1 = b2.y + wb0.x * u.x + wb0.y * u.y + wb0.z * u.z + wb0.w * u.w
                            + wb1.x * v.x + wb1.y * v.y + wb1.z * v.z + wb1.w * v.w;
            float2 hh = *(const float2*)(h_in + (size_t)src * WN + 2 * tc);
            acc0 += hh.x * w0;
            acc1 += hh.y * w1;
        }
        __syncthreads();
    }
    if (!valid) return;

    float invn = inv[node];
    float r0 = acc0 * invn + cb.x;
    float r1 = acc1 * invn + cb.y;
#pragma unroll
    for (int k = 0; k < WN; k++) {
        float hk = s_h[grp * 34 + k];
        float2 rt = *(const float2*)(root + k * WN + 2 * tc);   // L1-resident (4KB)
        r0 += hk * rt.x;
        r1 += hk * rt.y;
    }
    float2 o;
    o.x = r0 > 0.0f ? r0 : 0.0f;
    o.y = r1 > 0.0f ? r1 : 0.0f;
    *(float2*)(h_out + (size_t)node * WN + 2 * tc) = o;
}

__global__ void out_kernel(const float* __restrict__ h, const float* __restrict__ fc2_w,
                           const float* __restrict__ fc2_b, float* __restrict__ out, int n) {
    __shared__ float s_w[WN];
    __shared__ float s_b;
    int t = threadIdx.x;
    if (t < WN) s_w[t] = fc2_w[t];
    if (t == 0) s_b = fc2_b[0];
    __syncthreads();
    int i = blockIdx.x * blockDim.x + t;
    if (i >= n) return;
    float acc = s_b;
#pragma unroll
    for (int k = 0; k < WN; k++) acc += h[(size_t)i * WN + k] * s_w[k];
    out[i] = acc;
}

extern "C" void kernel_launch(void* const* d_in, const int* in_sizes, int n_in,
                              void* d_out, int out_size, void* d_ws, size_t ws_size,
                              hipStream_t stream) {
    const float* x      = (const float*)d_in[0];
    const int*   eidx   = (const int*)d_in[1];
    const float* ea     = (const float*)d_in[2];
    const float* fc1_w  = (const float*)d_in[3];
    const float* fc1_b  = (const float*)d_in[4];
    const float* fc2_w  = (const float*)d_in[5];
    const float* fc2_b  = (const float*)d_in[6];
    const float* kw1    = (const float*)d_in[7];
    const float* kb1    = (const float*)d_in[8];
    const float* kw2    = (const float*)d_in[9];
    const float* kb2    = (const float*)d_in[10];
    const float* root   = (const float*)d_in[11];
    const float* cbias  = (const float*)d_in[12];
    float* out = (float*)d_out;

    const int n = in_sizes[0] / 3;       // 50000
    const int e_cnt = in_sizes[2] / 3;   // 1600000

    // workspace layout (floats, 16B-aligned sections)
    auto pad4 = [](size_t v) { return (v + 3) & ~(size_t)3; };
    float* ws = (float*)d_ws;
    size_t off = 0;
    float* hA        = ws + off; off += pad4((size_t)n * WN);
    float* hB        = ws + off; off += pad4((size_t)n * WN);
    float* inv       = ws + off; off += pad4(n);
    int*   cnt       = (int*)(ws + off); off += pad4(n);
    int*   cursor    = (int*)(ws + off); off += pad4(n);
    int*   row_ptr   = (int*)(ws + off); off += pad4(n + 1);
    int*   order     = (int*)(ws + off); off += pad4(n);
    int*   bins      = (int*)(ws + off); off += NBIN;
    int*   bin_base  = (int*)(ws + off); off += NBIN;
    int*   bin_cur   = (int*)(ws + off); off += NBIN;
    fvec4* rec       = (fvec4*)(ws + off); off += (size_t)4 * e_cnt;

    const int B = 256;
    int grid_n  = (n + B - 1) / B;
    int grid_e  = (e_cnt + B - 1) / B;
    int grid_g  = (n + GPB - 1) / GPB;

    zero_kernel<<<grid_n, B, 0, stream>>>(cnt, cursor, bins, bin_cur, n);
    count_kernel<<<grid_e, B, 0, stream>>>(eidx, cnt, e_cnt);
    scan_kernel<<<1, 1024, 0, stream>>>(cnt, row_ptr, inv, bins, n);
    bin_scan_kernel<<<1, 1024, 0, stream>>>(bins, bin_base);
    order_kernel<<<grid_n, B, 0, stream>>>(cnt, bin_base, bin_cur, order, n);
    scatter_kernel<<<grid_e, B, 0, stream>>>(eidx, ea, row_ptr, cursor, rec, e_cnt);
    h0_kernel<<<grid_n, B, 0, stream>>>(x, fc1_w, fc1_b, hA, n);

    float* hin = hA;
    float* hout = hB;
    for (int d = 0; d < DEPTH; d++) {
        for (int c = 0; c < 3; c++) {
            gather2_kernel<<<grid_g, B, 0, stream>>>(
                row_ptr, rec, order, hin, hout, inv,
                kw1 + (size_t)c * HID * 3, kb1 + (size_t)c * HID,
                kw2 + (size_t)c * WN * HID, kb2 + (size_t)c * WN,
                root + (size_t)c * WN * WN, cbias + (size_t)c * WN, n);
            float* tmp = hin; hin = hout; hout = tmp;
        }
    }
    // 12 swaps -> final h is in hin
    out_kernel<<<grid_n, B, 0, stream>>>(hin, fc2_w, fc2_b, out, n);
}